// Round 1
// 1598.084 us; speedup vs baseline: 1.0272x; 1.0272x over previous
//
#include <hip/hip_runtime.h>
#include <math.h>
#include <stdint.h>

#define N_NODES 16384
#define E_EDGES 524288
#define E_TOT   (E_EDGES + N_NODES)   // 540672
#define HDIM    512                   // HEADS * OUT_CH
#define SLOPE   0.2f

typedef unsigned short ushort_t;
typedef __attribute__((ext_vector_type(8))) short short8v;  // 8 bf16 (4 VGPRs)
typedef __attribute__((ext_vector_type(4))) float f32x4;

// RNE float->bf16 bits, and back (bit ops; no header-version dependence)
__device__ __forceinline__ unsigned short f2bf(float f) {
    unsigned u = __float_as_uint(f);
    return (unsigned short)((u + 0x7fffu + ((u >> 16) & 1u)) >> 16);
}
__device__ __forceinline__ float bf2f(unsigned short s) {
    return __uint_as_float(((unsigned)s) << 16);
}

#define GLOAD_LDS16(G, L)                                                               \
    __builtin_amdgcn_global_load_lds((const __attribute__((address_space(1))) unsigned int*)(G), \
                                     (__attribute__((address_space(3))) unsigned int*)(L), 16, 0, 0)

// ---------------------------------------------------------------------------
// edge_index storage-width detection (int64 per reference vs int32 per harness)
__global__ void detect_kernel(const void* __restrict__ ei, int* __restrict__ flag) {
    int t = threadIdx.x;
    int v = ((const int*)ei)[2 * t + 1];
    unsigned long long b = __ballot(v != 0);
    if (t == 0) *flag = (b == 0ULL) ? 1 : 0;
}

__device__ __forceinline__ int edge_val(const void* ei, int idx, int is64) {
    if (is64) return (int)((const long long*)ei)[idx];
    return ((const int*)ei)[idx];
}

// ---------------------------------------------------------------------------
// CSR build
__global__ __launch_bounds__(256) void count_kernel(const void* __restrict__ ei,
                                                    const int* __restrict__ flag,
                                                    int* __restrict__ deg) {
    int e = blockIdx.x * 256 + threadIdx.x;
    if (e >= E_TOT) return;
    int is64 = *flag;
    int dst = (e < E_EDGES) ? edge_val(ei, E_EDGES + e, is64) : (e - E_EDGES);
    atomicAdd(&deg[dst], 1);
}

__global__ __launch_bounds__(1024) void scan_kernel(const int* __restrict__ deg,
                                                    int* __restrict__ rowptr,
                                                    int* __restrict__ cursor) {
    __shared__ int ps[1024];
    int tid = threadIdx.x;
    int base = tid * 16;
    int loc[16];
    int s = 0;
#pragma unroll
    for (int i = 0; i < 16; ++i) { loc[i] = deg[base + i]; s += loc[i]; }
    ps[tid] = s;
    __syncthreads();
    for (int off = 1; off < 1024; off <<= 1) {
        int t = (tid >= off) ? ps[tid - off] : 0;
        __syncthreads();
        if (tid >= off) ps[tid] += t;
        __syncthreads();
    }
    int run = ps[tid] - s;
#pragma unroll
    for (int i = 0; i < 16; ++i) {
        rowptr[base + i] = run;
        cursor[base + i] = run;
        run += loc[i];
    }
    if (tid == 1023) rowptr[N_NODES] = run;
}

__global__ __launch_bounds__(256) void fill_kernel(const void* __restrict__ ei,
                                                   const int* __restrict__ flag,
                                                   int* __restrict__ cursor,
                                                   int* __restrict__ col) {
    int e = blockIdx.x * 256 + threadIdx.x;
    if (e >= E_TOT) return;
    int is64 = *flag;
    int src, dst;
    if (e < E_EDGES) {
        src = edge_val(ei, e, is64);
        dst = edge_val(ei, E_EDGES + e, is64);
    } else {
        src = dst = e - E_EDGES;
    }
    int slot = atomicAdd(&cursor[dst], 1);
    col[slot] = src;
}

// ---------------------------------------------------------------------------
// fp32 -> split-bf16 K-concat:  dst[M,3K]
//  A-style (BSTYLE=false): [hi | hi | lo]   (pairs with B's [hi | lo | hi])
//  B-style (BSTYLE=true):  [hi | lo | hi]
// sum over 3K of A''*B'' = Ah*Bh + Ah*Bl + Al*Bh ~= fp32 product (drop Al*Bl)
template <bool BSTYLE>
__global__ __launch_bounds__(256) void split3_kernel(const float* __restrict__ src,
                                                     ushort_t* __restrict__ dst,
                                                     int kshift) {
    int idx = (blockIdx.x * 256 + threadIdx.x) * 4;
    int K = 1 << kshift;
    int row = idx >> kshift, c = idx & (K - 1);
    float4 v = *(const float4*)&src[idx];
    float f[4] = {v.x, v.y, v.z, v.w};
    ushort_t h4[4], l4[4];
#pragma unroll
    for (int q = 0; q < 4; ++q) {
        ushort_t hb = f2bf(f[q]);
        float r = f[q] - bf2f(hb);
        h4[q] = hb;
        l4[q] = f2bf(r);
    }
    size_t b = (size_t)row * (3 * (size_t)K) + c;
    *(ushort4*)&dst[b] = make_ushort4(h4[0], h4[1], h4[2], h4[3]);
    size_t off_hi2 = BSTYLE ? (size_t)(2 * K) : (size_t)K;
    size_t off_lo  = BSTYLE ? (size_t)K : (size_t)(2 * K);
    *(ushort4*)&dst[b + off_hi2] = make_ushort4(h4[0], h4[1], h4[2], h4[3]);
    *(ushort4*)&dst[b + off_lo]  = make_ushort4(l4[0], l4[1], l4[2], l4[3]);
}

// ---------------------------------------------------------------------------
// bf16 MFMA GEMM: C[M,N] = A[M,K] * B[N,K]^T (+bias,+relu), fp32 epilogue.
// BM=128, BK=64, 256 threads = 4 waves in 2x2 grid, each wave 64 x (BN/2).
// LDS: linear [rows][64] bf16 tiles; st-style XOR swizzle (col ^= (row&7)<<3
// in shorts) applied on BOTH the pre-swizzled global_load_lds source and the
// ds_read_b128 fragment reads (rule #21: both-sides-or-neither).
template <int BN, bool RELU, bool BIAS>
__global__ __launch_bounds__(256) void mfma_gemm(const ushort_t* __restrict__ A,
                                                 const ushort_t* __restrict__ B,
                                                 const float* __restrict__ bias,
                                                 float* __restrict__ C,
                                                 int M, int N, int K) {
    constexpr int BM = 128, BK = 64;
    constexpr int ASLOTS = BM * BK / (256 * 8);  // 4
    constexpr int BSLOTS = BN * BK / (256 * 8);  // 4 (BN=128) or 2 (BN=64)
    constexpr int BNF = BN / 32;                 // b-frags per wave
    __shared__ ushort_t As[BM * BK];
    __shared__ ushort_t Bs[BN * BK];

    int t = threadIdx.x;
    int bm0 = blockIdx.y * BM, bn0 = blockIdx.x * BN;

    // staging: slot s, thread t stages 16B; LDS dest linear, global source
    // carries the inverse swizzle so swizzled reads see the right data.
    size_t gA[ASLOTS]; int lA[ASLOTS];
#pragma unroll
    for (int s = 0; s < ASLOTS; ++s) {
        int lin = s * 256 + t;
        int row = lin >> 3, cs = (lin & 7) << 3;       // 8 shorts per chunk
        int lcol = cs ^ ((row & 7) << 3);
        gA[s] = (size_t)(bm0 + row) * K + lcol;
        lA[s] = (s * 256 + (t & ~63)) * 8;             // wave-uniform base
    }
    size_t gB[BSLOTS]; int lB[BSLOTS];
#pragma unroll
    for (int s = 0; s < BSLOTS; ++s) {
        int lin = s * 256 + t;
        int row = lin >> 3, cs = (lin & 7) << 3;
        int lcol = cs ^ ((row & 7) << 3);
        gB[s] = (size_t)(bn0 + row) * K + lcol;
        lB[s] = (s * 256 + (t & ~63)) * 8;
    }

    int l = t & 63, w = t >> 6;
    int wm = w >> 1, wn = w & 1;
    int lr = l & 15, lk = l >> 4;

    f32x4 acc[4][BNF];
#pragma unroll
    for (int m = 0; m < 4; ++m)
#pragma unroll
        for (int n = 0; n < BNF; ++n) acc[m][n] = (f32x4){0.f, 0.f, 0.f, 0.f};

    for (int k0 = 0; k0 < K; k0 += BK) {
#pragma unroll
        for (int s = 0; s < ASLOTS; ++s) GLOAD_LDS16(A + gA[s] + k0, As + lA[s]);
#pragma unroll
        for (int s = 0; s < BSLOTS; ++s) GLOAD_LDS16(B + gB[s] + k0, Bs + lB[s]);
        __syncthreads();   // compiler drains vmcnt before s_barrier
#pragma unroll
        for (int ks = 0; ks < 2; ++ks) {
            short8v af[4], bfr[BNF];
#pragma unroll
            for (int m = 0; m < 4; ++m) {
                int row = wm * 64 + m * 16 + lr;
                int c = (ks * 32 + lk * 8) ^ ((row & 7) << 3);
                af[m] = *(const short8v*)&As[row * 64 + c];
            }
#pragma unroll
            for (int n = 0; n < BNF; ++n) {
                int row = wn * (BN / 2) + n * 16 + lr;
                int c = (ks * 32 + lk * 8) ^ ((row & 7) << 3);
                bfr[n] = *(const short8v*)&Bs[row * 64 + c];
            }
#pragma unroll
            for (int m = 0; m < 4; ++m)
#pragma unroll
                for (int n = 0; n < BNF; ++n)
                    acc[m][n] = __builtin_amdgcn_mfma_f32_16x16x32_bf16(af[m], bfr[n],
                                                                        acc[m][n], 0, 0, 0);
        }
        __syncthreads();
    }

    // epilogue: C/D frag mapping col=lane&15, row=(lane>>4)*4+reg (m89/m91)
#pragma unroll
    for (int m = 0; m < 4; ++m) {
        int row0 = bm0 + wm * 64 + m * 16 + lk * 4;
#pragma unroll
        for (int n = 0; n < BNF; ++n) {
            int cix = bn0 + wn * (BN / 2) + n * 16 + lr;
            float bv = BIAS ? bias[cix] : 0.f;
#pragma unroll
            for (int r = 0; r < 4; ++r) {
                float v = acc[m][n][r] + bv;
                if (RELU) v = fmaxf(v, 0.f);
                C[(size_t)(row0 + r) * N + cix] = v;
            }
        }
    }
}

// ---------------------------------------------------------------------------
// attention logits a_src[n,h], a_dst[n,h]
__global__ __launch_bounds__(256) void attn_kernel(const float* __restrict__ h,
                                                   const float* __restrict__ att_src,
                                                   const float* __restrict__ att_dst,
                                                   float* __restrict__ a_src,
                                                   float* __restrict__ a_dst) {
    int n = blockIdx.x, tid = threadIdx.x;
    float h0 = h[(size_t)n * HDIM + tid];
    float h1 = h[(size_t)n * HDIM + 256 + tid];
    __shared__ float4 red[256];
    red[tid] = make_float4(h0 * att_src[tid], h1 * att_src[256 + tid],
                           h0 * att_dst[tid], h1 * att_dst[256 + tid]);
    __syncthreads();
    for (int off = 128; off > 0; off >>= 1) {
        if (tid < off) {
            float4 o = red[tid + off];
            float4 m = red[tid];
            m.x += o.x; m.y += o.y; m.z += o.z; m.w += o.w;
            red[tid] = m;
        }
        __syncthreads();
    }
    if (tid == 0) {
        float4 r = red[0];
        a_src[2 * n] = r.x; a_src[2 * n + 1] = r.y;
        a_dst[2 * n] = r.z; a_dst[2 * n + 1] = r.w;
    }
}

__device__ __forceinline__ float lrelu(float x) {
    return fmaxf(x, 0.f) + SLOPE * fminf(x, 0.f);
}

// ---------------------------------------------------------------------------
// per-dst-node segment softmax + weighted aggregation; writes relu(agg+bias)
__global__ __launch_bounds__(256) void aggregate_kernel(const float* __restrict__ h,
                                                        const float* __restrict__ a_src,
                                                        const float* __restrict__ a_dst,
                                                        const int* __restrict__ rowptr,
                                                        const int* __restrict__ col,
                                                        const float* __restrict__ conv_b,
                                                        float* __restrict__ act0) {
    int n = blockIdx.x, tid = threadIdx.x;
    int rs = rowptr[n], re = rowptr[n + 1];
    float ad0 = a_dst[2 * n], ad1 = a_dst[2 * n + 1];
    __shared__ float r0[256], r1[256];

    float m0 = -1e30f, m1 = -1e30f;
    for (int k = rs + tid; k < re; k += 256) {
        int s = col[k];
        float e0 = lrelu(a_src[2 * s] + ad0);
        float e1 = lrelu(a_src[2 * s + 1] + ad1);
        m0 = fmaxf(m0, e0); m1 = fmaxf(m1, e1);
    }
    r0[tid] = m0; r1[tid] = m1;
    __syncthreads();
    for (int off = 128; off > 0; off >>= 1) {
        if (tid < off) {
            r0[tid] = fmaxf(r0[tid], r0[tid + off]);
            r1[tid] = fmaxf(r1[tid], r1[tid + off]);
        }
        __syncthreads();
    }
    float M0 = r0[0], M1 = r1[0];
    __syncthreads();

    float s0 = 0.f, s1 = 0.f;
    for (int k = rs + tid; k < re; k += 256) {
        int s = col[k];
        float e0 = lrelu(a_src[2 * s] + ad0);
        float e1 = lrelu(a_src[2 * s + 1] + ad1);
        s0 += expf(e0 - M0); s1 += expf(e1 - M1);
    }
    r0[tid] = s0; r1[tid] = s1;
    __syncthreads();
    for (int off = 128; off > 0; off >>= 1) {
        if (tid < off) {
            r0[tid] += r0[tid + off];
            r1[tid] += r1[tid + off];
        }
        __syncthreads();
    }
    float inv0 = 1.f / r0[0], inv1 = 1.f / r1[0];
    __syncthreads();

    __shared__ float al0[256], al1[256];
    __shared__ int sc[256];
    float acc0 = 0.f, acc1 = 0.f;
    for (int base = rs; base < re; base += 256) {
        int len = min(256, re - base);
        if (tid < len) {
            int s = col[base + tid];
            sc[tid] = s;
            float e0 = lrelu(a_src[2 * s] + ad0);
            float e1 = lrelu(a_src[2 * s + 1] + ad1);
            al0[tid] = expf(e0 - M0) * inv0;
            al1[tid] = expf(e1 - M1) * inv1;
        }
        __syncthreads();
        for (int kk = 0; kk < len; ++kk) {
            const float* hr = h + (size_t)sc[kk] * HDIM;
            acc0 = fmaf(al0[kk], hr[tid], acc0);
            acc1 = fmaf(al1[kk], hr[tid + 256], acc1);
        }
        __syncthreads();
    }
    act0[(size_t)n * HDIM + tid] = fmaxf(acc0 + conv_b[tid], 0.f);
    act0[(size_t)n * HDIM + 256 + tid] = fmaxf(acc1 + conv_b[tid + 256], 0.f);
}

// ---------------------------------------------------------------------------
// fused MLP tail: 128 ->(relu) 64 ->(relu) 32 ->(none after W4) 3
__global__ __launch_bounds__(256) void mlp_tail_kernel(const float* __restrict__ act2,
                                                       const float* __restrict__ W2, const float* __restrict__ b2,
                                                       const float* __restrict__ W3, const float* __restrict__ b3,
                                                       const float* __restrict__ W4, const float* __restrict__ b4,
                                                       float* __restrict__ p) {
    __shared__ float w2[64][129];
    __shared__ float w3[32][65];
    __shared__ float w4[3][33];
    __shared__ float bb2[64], bb3[32], bb4[3];
    __shared__ float xb[4][128];
    __shared__ float yb[4][64];
    __shared__ float zb[4][32];
    int tid = threadIdx.x;
    for (int idx = tid; idx < 64 * 128; idx += 256) w2[idx >> 7][idx & 127] = W2[idx];
    for (int idx = tid; idx < 32 * 64; idx += 256) w3[idx >> 6][idx & 63] = W3[idx];
    for (int idx = tid; idx < 96; idx += 256) w4[idx / 32][idx % 32] = W4[idx];
    if (tid < 64) bb2[tid] = b2[tid];
    if (tid < 32) bb3[tid] = b3[tid];
    if (tid < 3) bb4[tid] = b4[tid];
    __syncthreads();

    int n0 = blockIdx.x * 64;
    int nl = tid >> 6, lane = tid & 63;
    for (int g = 0; g < 64; g += 4) {
        for (int lx = tid; lx < 512; lx += 256)
            xb[lx >> 7][lx & 127] = act2[(size_t)(n0 + g + (lx >> 7)) * 128 + (lx & 127)];
        __syncthreads();
        float y = bb2[lane];
#pragma unroll 8
        for (int j = 0; j < 128; ++j) y = fmaf(w2[lane][j], xb[nl][j], y);
        yb[nl][lane] = fmaxf(y, 0.f);
        __syncthreads();
        if (lane < 32) {
            float z = bb3[lane];
#pragma unroll 8
            for (int j = 0; j < 64; ++j) z = fmaf(w3[lane][j], yb[nl][j], z);
            zb[nl][lane] = fmaxf(z, 0.f);
        }
        __syncthreads();
        if (lane < 3) {
            float c = bb4[lane];
#pragma unroll
            for (int j = 0; j < 32; ++j) c = fmaf(w4[lane][j], zb[nl][j], c);
            p[(size_t)(n0 + g + nl) * 3 + lane] = c;
        }
        __syncthreads();
    }
}

// ---------------------------------------------------------------------------
// pairwise distances via direct diffs
__global__ __launch_bounds__(256) void cdist_kernel(const float* __restrict__ p,
                                                    float* __restrict__ out) {
    int tid = threadIdx.x;
    int j0 = blockIdx.x * 1024 + tid * 4;
    int i0 = blockIdx.y * 64;
    __shared__ float pi[64][3];
    for (int lx = tid; lx < 192; lx += 256) pi[lx / 3][lx % 3] = p[i0 * 3 + lx];
    float px[4], py[4], pz[4];
#pragma unroll
    for (int q = 0; q < 4; ++q) {
        const float* pp = p + (size_t)(j0 + q) * 3;
        px[q] = pp[0]; py[q] = pp[1]; pz[q] = pp[2];
    }
    __syncthreads();
#pragma unroll 4
    for (int i = 0; i < 64; ++i) {
        float ax = pi[i][0], ay = pi[i][1], az = pi[i][2];
        float o[4];
#pragma unroll
        for (int q = 0; q < 4; ++q) {
            float dx = ax - px[q], dy = ay - py[q], dz = az - pz[q];
            float d2 = fmaf(dx, dx, fmaf(dy, dy, dz * dz));
            o[q] = (d2 > 0.f) ? sqrtf(d2) : 0.f;
        }
        *(float4*)(out + (size_t)(i0 + i) * N_NODES + j0) = make_float4(o[0], o[1], o[2], o[3]);
    }
}

// ---------------------------------------------------------------------------
extern "C" void kernel_launch(void* const* d_in, const int* in_sizes, int n_in,
                              void* d_out, int out_size, void* d_ws, size_t ws_size,
                              hipStream_t stream) {
    const float* x       = (const float*)d_in[0];
    const void*  ei      = d_in[1];
    const float* conv_W  = (const float*)d_in[2];
    const float* att_src = (const float*)d_in[3];
    const float* att_dst = (const float*)d_in[4];
    const float* conv_b  = (const float*)d_in[5];
    const float* Wa = (const float*)d_in[6];  const float* ba = (const float*)d_in[7];
    const float* W1 = (const float*)d_in[8];  const float* b1 = (const float*)d_in[9];
    const float* W2 = (const float*)d_in[10]; const float* b2 = (const float*)d_in[11];
    const float* W3 = (const float*)d_in[12]; const float* b3 = (const float*)d_in[13];
    const float* W4 = (const float*)d_in[14]; const float* b4 = (const float*)d_in[15];
    float* out = (float*)d_out;

    // fp32 workspace
    float* ws_f  = (float*)d_ws;
    float* h     = ws_f;                              // 16384*512
    float* act0  = h     + (size_t)N_NODES * HDIM;    // 16384*512
    float* act1  = act0  + (size_t)N_NODES * HDIM;    // 16384*256
    float* act2  = act1  + (size_t)N_NODES * 256;     // 16384*128
    float* p3    = act2  + (size_t)N_NODES * 128;     // 16384*4 (padded)
    float* a_src = p3    + (size_t)N_NODES * 4;       // 16384*2
    float* a_dst = a_src + N_NODES * 2;               // 16384*2
    int* deg     = (int*)(a_dst + N_NODES * 2);       // 16384
    int* rowptr  = deg + N_NODES;                     // 16385
    int* cursor  = rowptr + N_NODES + 1;              // 16384
    int* colx    = cursor + N_NODES;                  // 540672
    int* flag    = colx + E_TOT;                      // 1
    // split-bf16 buffers (256B-aligned start; each size is 16B-multiple)
    uintptr_t up = ((uintptr_t)(flag + 1) + 255) & ~(uintptr_t)255;
    ushort_t* x2  = (ushort_t*)up;                    // 16384*768
    ushort_t* a02 = x2  + (size_t)N_NODES * 768;      // 16384*1536
    ushort_t* a12 = a02 + (size_t)N_NODES * 1536;     // 16384*768
    ushort_t* cw2 = a12 + (size_t)N_NODES * 768;      // 512*768
    ushort_t* wa2 = cw2 + (size_t)512 * 768;          // 256*1536
    ushort_t* w12 = wa2 + (size_t)256 * 1536;         // 128*768

    hipMemsetAsync(deg, 0, N_NODES * sizeof(int), stream);
    detect_kernel<<<1, 64, 0, stream>>>(ei, flag);

    // split-bf16 conversions (A-style for activations, B-style for weights)
    split3_kernel<false><<<N_NODES * 256 / 1024, 256, 0, stream>>>(x, x2, 8);
    split3_kernel<true><<<512 * 256 / 1024, 256, 0, stream>>>(conv_W, cw2, 8);
    split3_kernel<true><<<256 * 512 / 1024, 256, 0, stream>>>(Wa, wa2, 9);
    split3_kernel<true><<<128 * 256 / 1024, 256, 0, stream>>>(W1, w12, 8);

    // h = x @ conv_W^T  [16384,512]  (K' = 3*256 = 768)
    mfma_gemm<128, false, false><<<dim3(4, 128), 256, 0, stream>>>(
        x2, cw2, nullptr, h, N_NODES, 512, 768);

    attn_kernel<<<N_NODES, 256, 0, stream>>>(h, att_src, att_dst, a_src, a_dst);

    count_kernel<<<E_TOT / 256, 256, 0, stream>>>(ei, flag, deg);
    scan_kernel<<<1, 1024, 0, stream>>>(deg, rowptr, cursor);
    fill_kernel<<<E_TOT / 256, 256, 0, stream>>>(ei, flag, cursor, colx);

    aggregate_kernel<<<N_NODES, 256, 0, stream>>>(h, a_src, a_dst, rowptr, colx,
                                                  conv_b, act0);

    // act1 = relu(act0 @ Wa^T + ba)  [16384,256]  (K' = 3*512 = 1536)
    split3_kernel<false><<<N_NODES * 512 / 1024, 256, 0, stream>>>(act0, a02, 9);
    mfma_gemm<128, true, true><<<dim3(2, 128), 256, 0, stream>>>(
        a02, wa2, ba, act1, N_NODES, 256, 1536);

    // act2 = relu(act1 @ W1^T + b1)  [16384,128]  (K' = 3*256 = 768)
    split3_kernel<false><<<N_NODES * 256 / 1024, 256, 0, stream>>>(act1, a12, 8);
    mfma_gemm<64, true, true><<<dim3(2, 128), 256, 0, stream>>>(
        a12, w12, b1, act2, N_NODES, 128, 768);

    // p3 = tail MLP  [16384,3]
    mlp_tail_kernel<<<N_NODES / 64, 256, 0, stream>>>(act2, W2, b2, W3, b3, W4, b4, p3);

    // out = pairwise distances [16384,16384]
    cdist_kernel<<<dim3(16, 256), 256, 0, stream>>>(p3, out);
}

// Round 2
// 1583.511 us; speedup vs baseline: 1.0367x; 1.0092x over previous
//
#include <hip/hip_runtime.h>
#include <math.h>
#include <stdint.h>

#define N_NODES 16384
#define E_EDGES 524288
#define E_TOT   (E_EDGES + N_NODES)   // 540672
#define HDIM    512                   // HEADS * OUT_CH
#define SLOPE   0.2f

typedef unsigned short ushort_t;
typedef __attribute__((ext_vector_type(8))) short short8v;  // 8 bf16 (4 VGPRs)
typedef __attribute__((ext_vector_type(4))) float f32x4;

// RNE float->bf16 bits, and back
__device__ __forceinline__ unsigned short f2bf(float f) {
    unsigned u = __float_as_uint(f);
    return (unsigned short)((u + 0x7fffu + ((u >> 16) & 1u)) >> 16);
}
__device__ __forceinline__ float bf2f(unsigned short s) {
    return __uint_as_float(((unsigned)s) << 16);
}

#define GLOAD_LDS16(G, L)                                                               \
    __builtin_amdgcn_global_load_lds((const __attribute__((address_space(1))) unsigned int*)(G), \
                                     (__attribute__((address_space(3))) unsigned int*)(L), 16, 0, 0)

// ---------------------------------------------------------------------------
// edge_index storage-width detection
__global__ void detect_kernel(const void* __restrict__ ei, int* __restrict__ flag) {
    int t = threadIdx.x;
    int v = ((const int*)ei)[2 * t + 1];
    unsigned long long b = __ballot(v != 0);
    if (t == 0) *flag = (b == 0ULL) ? 1 : 0;
}

__device__ __forceinline__ int edge_val(const void* ei, int idx, int is64) {
    if (is64) return (int)((const long long*)ei)[idx];
    return ((const int*)ei)[idx];
}

// ---------------------------------------------------------------------------
// CSR build
__global__ __launch_bounds__(256) void count_kernel(const void* __restrict__ ei,
                                                    const int* __restrict__ flag,
                                                    int* __restrict__ deg) {
    int e = blockIdx.x * 256 + threadIdx.x;
    if (e >= E_TOT) return;
    int is64 = *flag;
    int dst = (e < E_EDGES) ? edge_val(ei, E_EDGES + e, is64) : (e - E_EDGES);
    atomicAdd(&deg[dst], 1);
}

__global__ __launch_bounds__(1024) void scan_kernel(const int* __restrict__ deg,
                                                    int* __restrict__ rowptr,
                                                    int* __restrict__ cursor) {
    __shared__ int ps[1024];
    int tid = threadIdx.x;
    int base = tid * 16;
    int loc[16];
    int s = 0;
#pragma unroll
    for (int i = 0; i < 16; ++i) { loc[i] = deg[base + i]; s += loc[i]; }
    ps[tid] = s;
    __syncthreads();
    for (int off = 1; off < 1024; off <<= 1) {
        int t = (tid >= off) ? ps[tid - off] : 0;
        __syncthreads();
        if (tid >= off) ps[tid] += t;
        __syncthreads();
    }
    int run = ps[tid] - s;
#pragma unroll
    for (int i = 0; i < 16; ++i) {
        rowptr[base + i] = run;
        cursor[base + i] = run;
        run += loc[i];
    }
    if (tid == 1023) rowptr[N_NODES] = run;
}

__global__ __launch_bounds__(256) void fill_kernel(const void* __restrict__ ei,
                                                   const int* __restrict__ flag,
                                                   int* __restrict__ cursor,
                                                   int* __restrict__ col) {
    int e = blockIdx.x * 256 + threadIdx.x;
    if (e >= E_TOT) return;
    int is64 = *flag;
    int src, dst;
    if (e < E_EDGES) {
        src = edge_val(ei, e, is64);
        dst = edge_val(ei, E_EDGES + e, is64);
    } else {
        src = dst = e - E_EDGES;
    }
    int slot = atomicAdd(&cursor[dst], 1);
    col[slot] = src;
}

// ---------------------------------------------------------------------------
// fp32 -> split-bf16 K-concat (inputs only):
//  A-style (BSTYLE=false): [hi | hi | lo], B-style (BSTYLE=true): [hi | lo | hi]
template <bool BSTYLE>
__global__ __launch_bounds__(256) void split3_kernel(const float* __restrict__ src,
                                                     ushort_t* __restrict__ dst,
                                                     int kshift) {
    int idx = (blockIdx.x * 256 + threadIdx.x) * 4;
    int K = 1 << kshift;
    int row = idx >> kshift, c = idx & (K - 1);
    float4 v = *(const float4*)&src[idx];
    float f[4] = {v.x, v.y, v.z, v.w};
    ushort_t h4[4], l4[4];
#pragma unroll
    for (int q = 0; q < 4; ++q) {
        ushort_t hb = f2bf(f[q]);
        float r = f[q] - bf2f(hb);
        h4[q] = hb;
        l4[q] = f2bf(r);
    }
    size_t b = (size_t)row * (3 * (size_t)K) + c;
    *(ushort4*)&dst[b] = make_ushort4(h4[0], h4[1], h4[2], h4[3]);
    size_t off_hi2 = BSTYLE ? (size_t)(2 * K) : (size_t)K;
    size_t off_lo  = BSTYLE ? (size_t)K : (size_t)(2 * K);
    *(ushort4*)&dst[b + off_hi2] = make_ushort4(h4[0], h4[1], h4[2], h4[3]);
    *(ushort4*)&dst[b + off_lo]  = make_ushort4(l4[0], l4[1], l4[2], l4[3]);
}

// ---------------------------------------------------------------------------
// bf16 MFMA GEMM: C = A[M,K] * B[N,K]^T. BM=128, BK=64, 4 waves (2x2).
// OUTMODE: 0 = fp32 plain, 1 = fp32 bias+relu, 2 = bias+relu -> split-bf16 A-layout
template <int BN, int OUTMODE>
__global__ __launch_bounds__(256) void mfma_gemm(const ushort_t* __restrict__ A,
                                                 const ushort_t* __restrict__ B,
                                                 const float* __restrict__ bias,
                                                 float* __restrict__ Cf,
                                                 ushort_t* __restrict__ Cs,
                                                 int M, int N, int K) {
    constexpr int BM = 128, BK = 64;
    constexpr int ASLOTS = BM * BK / (256 * 8);  // 4
    constexpr int BSLOTS = BN * BK / (256 * 8);  // 4 or 2
    constexpr int BNF = BN / 32;
    __shared__ ushort_t As[BM * BK];
    __shared__ ushort_t Bs[BN * BK];

    int t = threadIdx.x;
    int bm0 = blockIdx.y * BM, bn0 = blockIdx.x * BN;

    size_t gA[ASLOTS]; int lA[ASLOTS];
#pragma unroll
    for (int s = 0; s < ASLOTS; ++s) {
        int lin = s * 256 + t;
        int row = lin >> 3, cs = (lin & 7) << 3;
        int lcol = cs ^ ((row & 7) << 3);
        gA[s] = (size_t)(bm0 + row) * K + lcol;
        lA[s] = (s * 256 + (t & ~63)) * 8;
    }
    size_t gB[BSLOTS]; int lB[BSLOTS];
#pragma unroll
    for (int s = 0; s < BSLOTS; ++s) {
        int lin = s * 256 + t;
        int row = lin >> 3, cs = (lin & 7) << 3;
        int lcol = cs ^ ((row & 7) << 3);
        gB[s] = (size_t)(bn0 + row) * K + lcol;
        lB[s] = (s * 256 + (t & ~63)) * 8;
    }

    int l = t & 63, w = t >> 6;
    int wm = w >> 1, wn = w & 1;
    int lr = l & 15, lk = l >> 4;

    f32x4 acc[4][BNF];
#pragma unroll
    for (int m = 0; m < 4; ++m)
#pragma unroll
        for (int n = 0; n < BNF; ++n) acc[m][n] = (f32x4){0.f, 0.f, 0.f, 0.f};

    for (int k0 = 0; k0 < K; k0 += BK) {
#pragma unroll
        for (int s = 0; s < ASLOTS; ++s) GLOAD_LDS16(A + gA[s] + k0, As + lA[s]);
#pragma unroll
        for (int s = 0; s < BSLOTS; ++s) GLOAD_LDS16(B + gB[s] + k0, Bs + lB[s]);
        __syncthreads();
#pragma unroll
        for (int ks = 0; ks < 2; ++ks) {
            short8v af[4], bfr[BNF];
#pragma unroll
            for (int m = 0; m < 4; ++m) {
                int row = wm * 64 + m * 16 + lr;
                int c = (ks * 32 + lk * 8) ^ ((row & 7) << 3);
                af[m] = *(const short8v*)&As[row * 64 + c];
            }
#pragma unroll
            for (int n = 0; n < BNF; ++n) {
                int row = wn * (BN / 2) + n * 16 + lr;
                int c = (ks * 32 + lk * 8) ^ ((row & 7) << 3);
                bfr[n] = *(const short8v*)&Bs[row * 64 + c];
            }
#pragma unroll
            for (int m = 0; m < 4; ++m)
#pragma unroll
                for (int n = 0; n < BNF; ++n)
                    acc[m][n] = __builtin_amdgcn_mfma_f32_16x16x32_bf16(af[m], bfr[n],
                                                                        acc[m][n], 0, 0, 0);
        }
        __syncthreads();
    }

#pragma unroll
    for (int m = 0; m < 4; ++m) {
        int row0 = bm0 + wm * 64 + m * 16 + lk * 4;
#pragma unroll
        for (int n = 0; n < BNF; ++n) {
            int cix = bn0 + wn * (BN / 2) + n * 16 + lr;
            float bv = (OUTMODE >= 1) ? bias[cix] : 0.f;
#pragma unroll
            for (int r = 0; r < 4; ++r) {
                float v = acc[m][n][r] + bv;
                if (OUTMODE >= 1) v = fmaxf(v, 0.f);
                if (OUTMODE == 2) {
                    ushort_t hb = f2bf(v);
                    ushort_t lb = f2bf(v - bf2f(hb));
                    size_t rb = (size_t)(row0 + r) * (3 * (size_t)N);
                    Cs[rb + cix] = hb;
                    Cs[rb + N + cix] = hb;
                    Cs[rb + 2 * N + cix] = lb;
                } else {
                    Cf[(size_t)(row0 + r) * N + cix] = v;
                }
            }
        }
    }
}

// ---------------------------------------------------------------------------
// attention logits a_src[n,h], a_dst[n,h]
__global__ __launch_bounds__(256) void attn_kernel(const float* __restrict__ h,
                                                   const float* __restrict__ att_src,
                                                   const float* __restrict__ att_dst,
                                                   float* __restrict__ a_src,
                                                   float* __restrict__ a_dst) {
    int n = blockIdx.x, tid = threadIdx.x;
    float h0 = h[(size_t)n * HDIM + tid];
    float h1 = h[(size_t)n * HDIM + 256 + tid];
    __shared__ float4 red[256];
    red[tid] = make_float4(h0 * att_src[tid], h1 * att_src[256 + tid],
                           h0 * att_dst[tid], h1 * att_dst[256 + tid]);
    __syncthreads();
    for (int off = 128; off > 0; off >>= 1) {
        if (tid < off) {
            float4 o = red[tid + off];
            float4 m = red[tid];
            m.x += o.x; m.y += o.y; m.z += o.z; m.w += o.w;
            red[tid] = m;
        }
        __syncthreads();
    }
    if (tid == 0) {
        float4 r = red[0];
        a_src[2 * n] = r.x; a_src[2 * n + 1] = r.y;
        a_dst[2 * n] = r.z; a_dst[2 * n + 1] = r.w;
    }
}

__device__ __forceinline__ float lrelu(float x) {
    return fmaxf(x, 0.f) + SLOPE * fminf(x, 0.f);
}

// ---------------------------------------------------------------------------
// wave-per-node segment softmax + aggregation, barrier-free.
// Writes relu(agg + conv_b) directly as split-bf16 A-layout a02[N,1536].
// Lane layout: lane owns head0 channels [lane*4,lane*4+4) and
//              head1 channels [256+lane*4, 256+lane*4+4).
__global__ __launch_bounds__(256) void aggregate_kernel(const float* __restrict__ h,
                                                        const float* __restrict__ a_src,
                                                        const float* __restrict__ a_dst,
                                                        const int* __restrict__ rowptr,
                                                        const int* __restrict__ col,
                                                        const float* __restrict__ conv_b,
                                                        ushort_t* __restrict__ a02) {
    int n = (blockIdx.x * 256 + threadIdx.x) >> 6;  // one wave per node
    int lane = threadIdx.x & 63;
    int rs = rowptr[n], re = rowptr[n + 1];
    float ad0 = a_dst[2 * n], ad1 = a_dst[2 * n + 1];

    // pass 1: segment max (strided over edges, shuffle-reduced)
    float m0 = -1e30f, m1 = -1e30f;
    for (int k = rs + lane; k < re; k += 64) {
        int s = col[k];
        float2 av = *(const float2*)&a_src[2 * s];
        m0 = fmaxf(m0, lrelu(av.x + ad0));
        m1 = fmaxf(m1, lrelu(av.y + ad1));
    }
#pragma unroll
    for (int off = 32; off > 0; off >>= 1) {
        m0 = fmaxf(m0, __shfl_xor(m0, off));
        m1 = fmaxf(m1, __shfl_xor(m1, off));
    }

    // pass 2: unnormalized weighted accumulation + denominator
    float4 acc0 = make_float4(0.f, 0.f, 0.f, 0.f);
    float4 acc1 = make_float4(0.f, 0.f, 0.f, 0.f);
    float s0 = 0.f, s1 = 0.f;
    for (int base = rs; base < re; base += 64) {
        int k = base + lane;
        int cnt = min(64, re - base);
        float w0 = 0.f, w1 = 0.f;
        int sv = 0;
        if (k < re) {
            sv = col[k];
            float2 av = *(const float2*)&a_src[2 * sv];
            w0 = expf(lrelu(av.x + ad0) - m0);
            w1 = expf(lrelu(av.y + ad1) - m1);
            s0 += w0; s1 += w1;
        }
#pragma unroll 4
        for (int kk = 0; kk < cnt; ++kk) {
            int sj = __shfl(sv, kk);
            float w0j = __shfl(w0, kk);
            float w1j = __shfl(w1, kk);
            const float* hr = h + (size_t)sj * HDIM;
            float4 hv0 = *(const float4*)&hr[lane * 4];
            float4 hv1 = *(const float4*)&hr[256 + lane * 4];
            acc0.x = fmaf(w0j, hv0.x, acc0.x);
            acc0.y = fmaf(w0j, hv0.y, acc0.y);
            acc0.z = fmaf(w0j, hv0.z, acc0.z);
            acc0.w = fmaf(w0j, hv0.w, acc0.w);
            acc1.x = fmaf(w1j, hv1.x, acc1.x);
            acc1.y = fmaf(w1j, hv1.y, acc1.y);
            acc1.z = fmaf(w1j, hv1.z, acc1.z);
            acc1.w = fmaf(w1j, hv1.w, acc1.w);
        }
    }
#pragma unroll
    for (int off = 32; off > 0; off >>= 1) {
        s0 += __shfl_xor(s0, off);
        s1 += __shfl_xor(s1, off);
    }
    float i0 = 1.f / s0, i1 = 1.f / s1;

    // epilogue: scale, bias, relu, split-bf16 [hi|hi|lo] over K=512
    float4 b0 = *(const float4*)&conv_b[lane * 4];
    float4 b1 = *(const float4*)&conv_b[256 + lane * 4];
    float v0[4] = {fmaxf(acc0.x * i0 + b0.x, 0.f), fmaxf(acc0.y * i0 + b0.y, 0.f),
                   fmaxf(acc0.z * i0 + b0.z, 0.f), fmaxf(acc0.w * i0 + b0.w, 0.f)};
    float v1[4] = {fmaxf(acc1.x * i1 + b1.x, 0.f), fmaxf(acc1.y * i1 + b1.y, 0.f),
                   fmaxf(acc1.z * i1 + b1.z, 0.f), fmaxf(acc1.w * i1 + b1.w, 0.f)};
    ushort_t h0[4], l0[4], h1v[4], l1[4];
#pragma unroll
    for (int q = 0; q < 4; ++q) {
        h0[q] = f2bf(v0[q]); l0[q] = f2bf(v0[q] - bf2f(h0[q]));
        h1v[q] = f2bf(v1[q]); l1[q] = f2bf(v1[q] - bf2f(h1v[q]));
    }
    size_t rb = (size_t)n * 1536;
    ushort4 uh0 = make_ushort4(h0[0], h0[1], h0[2], h0[3]);
    ushort4 ul0 = make_ushort4(l0[0], l0[1], l0[2], l0[3]);
    ushort4 uh1 = make_ushort4(h1v[0], h1v[1], h1v[2], h1v[3]);
    ushort4 ul1 = make_ushort4(l1[0], l1[1], l1[2], l1[3]);
    *(ushort4*)&a02[rb + lane * 4]        = uh0;   // head0 hi
    *(ushort4*)&a02[rb + 512 + lane * 4]  = uh0;   // head0 hi (2nd copy)
    *(ushort4*)&a02[rb + 1024 + lane * 4] = ul0;   // head0 lo
    *(ushort4*)&a02[rb + 256 + lane * 4]  = uh1;   // head1 hi
    *(ushort4*)&a02[rb + 768 + lane * 4]  = uh1;   // head1 hi (2nd copy)
    *(ushort4*)&a02[rb + 1280 + lane * 4] = ul1;   // head1 lo
}

// ---------------------------------------------------------------------------
// fused MLP tail: 128 ->(relu) 64 ->(relu) 32 -> 3
__global__ __launch_bounds__(256) void mlp_tail_kernel(const float* __restrict__ act2,
                                                       const float* __restrict__ W2, const float* __restrict__ b2,
                                                       const float* __restrict__ W3, const float* __restrict__ b3,
                                                       const float* __restrict__ W4, const float* __restrict__ b4,
                                                       float* __restrict__ p) {
    __shared__ float w2[64][129];
    __shared__ float w3[32][65];
    __shared__ float w4[3][33];
    __shared__ float bb2[64], bb3[32], bb4[3];
    __shared__ float xb[4][128];
    __shared__ float yb[4][64];
    __shared__ float zb[4][32];
    int tid = threadIdx.x;
    for (int idx = tid; idx < 64 * 128; idx += 256) w2[idx >> 7][idx & 127] = W2[idx];
    for (int idx = tid; idx < 32 * 64; idx += 256) w3[idx >> 6][idx & 63] = W3[idx];
    for (int idx = tid; idx < 96; idx += 256) w4[idx / 32][idx % 32] = W4[idx];
    if (tid < 64) bb2[tid] = b2[tid];
    if (tid < 32) bb3[tid] = b3[tid];
    if (tid < 3) bb4[tid] = b4[tid];
    __syncthreads();

    int n0 = blockIdx.x * 64;
    int nl = tid >> 6, lane = tid & 63;
    for (int g = 0; g < 64; g += 4) {
        for (int lx = tid; lx < 512; lx += 256)
            xb[lx >> 7][lx & 127] = act2[(size_t)(n0 + g + (lx >> 7)) * 128 + (lx & 127)];
        __syncthreads();
        float y = bb2[lane];
#pragma unroll 8
        for (int j = 0; j < 128; ++j) y = fmaf(w2[lane][j], xb[nl][j], y);
        yb[nl][lane] = fmaxf(y, 0.f);
        __syncthreads();
        if (lane < 32) {
            float z = bb3[lane];
#pragma unroll 8
            for (int j = 0; j < 64; ++j) z = fmaf(w3[lane][j], yb[nl][j], z);
            zb[nl][lane] = fmaxf(z, 0.f);
        }
        __syncthreads();
        if (lane < 3) {
            float c = bb4[lane];
#pragma unroll
            for (int j = 0; j < 32; ++j) c = fmaf(w4[lane][j], zb[nl][j], c);
            p[(size_t)(n0 + g + nl) * 3 + lane] = c;
        }
        __syncthreads();
    }
}

// ---------------------------------------------------------------------------
// pairwise distances via direct diffs
__global__ __launch_bounds__(256) void cdist_kernel(const float* __restrict__ p,
                                                    float* __restrict__ out) {
    int tid = threadIdx.x;
    int j0 = blockIdx.x * 1024 + tid * 4;
    int i0 = blockIdx.y * 64;
    __shared__ float pi[64][3];
    for (int lx = tid; lx < 192; lx += 256) pi[lx / 3][lx % 3] = p[i0 * 3 + lx];
    float px[4], py[4], pz[4];
#pragma unroll
    for (int q = 0; q < 4; ++q) {
        const float* pp = p + (size_t)(j0 + q) * 3;
        px[q] = pp[0]; py[q] = pp[1]; pz[q] = pp[2];
    }
    __syncthreads();
#pragma unroll 4
    for (int i = 0; i < 64; ++i) {
        float ax = pi[i][0], ay = pi[i][1], az = pi[i][2];
        float o[4];
#pragma unroll
        for (int q = 0; q < 4; ++q) {
            float dx = ax - px[q], dy = ay - py[q], dz = az - pz[q];
            float d2 = fmaf(dx, dx, fmaf(dy, dy, dz * dz));
            o[q] = (d2 > 0.f) ? sqrtf(d2) : 0.f;
        }
        *(float4*)(out + (size_t)(i0 + i) * N_NODES + j0) = make_float4(o[0], o[1], o[2], o[3]);
    }
}

// ---------------------------------------------------------------------------
extern "C" void kernel_launch(void* const* d_in, const int* in_sizes, int n_in,
                              void* d_out, int out_size, void* d_ws, size_t ws_size,
                              hipStream_t stream) {
    const float* x       = (const float*)d_in[0];
    const void*  ei      = d_in[1];
    const float* conv_W  = (const float*)d_in[2];
    const float* att_src = (const float*)d_in[3];
    const float* att_dst = (const float*)d_in[4];
    const float* conv_b  = (const float*)d_in[5];
    const float* Wa = (const float*)d_in[6];  const float* ba = (const float*)d_in[7];
    const float* W1 = (const float*)d_in[8];  const float* b1 = (const float*)d_in[9];
    const float* W2 = (const float*)d_in[10]; const float* b2 = (const float*)d_in[11];
    const float* W3 = (const float*)d_in[12]; const float* b3 = (const float*)d_in[13];
    const float* W4 = (const float*)d_in[14]; const float* b4 = (const float*)d_in[15];
    float* out = (float*)d_out;

    float* ws_f  = (float*)d_ws;
    float* h     = ws_f;                              // 16384*512 fp32
    float* act2  = h     + (size_t)N_NODES * HDIM;    // 16384*128 fp32
    float* p3    = act2  + (size_t)N_NODES * 128;     // 16384*4 (padded)
    float* a_src = p3    + (size_t)N_NODES * 4;       // 16384*2
    float* a_dst = a_src + N_NODES * 2;               // 16384*2
    int* deg     = (int*)(a_dst + N_NODES * 2);       // 16384
    int* rowptr  = deg + N_NODES;                     // 16385
    int* cursor  = rowptr + N_NODES + 1;              // 16384
    int* colx    = cursor + N_NODES;                  // 540672
    int* flag    = colx + E_TOT;                      // 1
    uintptr_t up = ((uintptr_t)(flag + 1) + 255) & ~(uintptr_t)255;
    ushort_t* x2  = (ushort_t*)up;                    // 16384*768
    ushort_t* a02 = x2  + (size_t)N_NODES * 768;      // 16384*1536
    ushort_t* a12 = a02 + (size_t)N_NODES * 1536;     // 16384*768
    ushort_t* cw2 = a12 + (size_t)N_NODES * 768;      // 512*768
    ushort_t* wa2 = cw2 + (size_t)512 * 768;          // 256*1536
    ushort_t* w12 = wa2 + (size_t)256 * 1536;         // 128*768

    hipMemsetAsync(deg, 0, N_NODES * sizeof(int), stream);
    detect_kernel<<<1, 64, 0, stream>>>(ei, flag);

    // input splits
    split3_kernel<false><<<N_NODES * 256 / 1024, 256, 0, stream>>>(x, x2, 8);
    split3_kernel<true><<<512 * 256 / 1024, 256, 0, stream>>>(conv_W, cw2, 8);
    split3_kernel<true><<<256 * 512 / 1024, 256, 0, stream>>>(Wa, wa2, 9);
    split3_kernel<true><<<128 * 256 / 1024, 256, 0, stream>>>(W1, w12, 8);

    // h = x @ conv_W^T  [16384,512]
    mfma_gemm<128, 0><<<dim3(4, 128), 256, 0, stream>>>(x2, cw2, nullptr, h, nullptr,
                                                        N_NODES, 512, 768);

    attn_kernel<<<N_NODES, 256, 0, stream>>>(h, att_src, att_dst, a_src, a_dst);

    count_kernel<<<E_TOT / 256, 256, 0, stream>>>(ei, flag, deg);
    scan_kernel<<<1, 1024, 0, stream>>>(deg, rowptr, cursor);
    fill_kernel<<<E_TOT / 256, 256, 0, stream>>>(ei, flag, cursor, colx);

    // aggregation -> a02 (split-bf16 of relu(agg+bias)), wave-per-node
    aggregate_kernel<<<N_NODES / 4, 256, 0, stream>>>(h, a_src, a_dst, rowptr, colx,
                                                      conv_b, a02);

    // act1(split) = relu(a02 @ Wa^T + ba) -> a12  [16384,256]
    mfma_gemm<128, 2><<<dim3(2, 128), 256, 0, stream>>>(a02, wa2, ba, nullptr, a12,
                                                        N_NODES, 256, 1536);
    // act2 = relu(a12 @ W1^T + b1)  [16384,128] fp32
    mfma_gemm<64, 1><<<dim3(2, 128), 256, 0, stream>>>(a12, w12, b1, act2, nullptr,
                                                       N_NODES, 128, 768);

    // p3 = tail MLP
    mlp_tail_kernel<<<N_NODES / 64, 256, 0, stream>>>(act2, W2, b2, W3, b3, W4, b4, p3);

    // out = pairwise distances
    cdist_kernel<<<dim3(16, 256), 256, 0, stream>>>(p3, out);
}